// Round 7
// baseline (224.994 us; speedup 1.0000x reference)
//
#include <hip/hip_runtime.h>
#include <stdint.h>

#define DM   1024
#define NH   16
#define DKc  64
#define Bc   4
#define Sc   2048
#define BSc  (Bc*Sc)

typedef float  f32x4   __attribute__((ext_vector_type(4)));
typedef float  f32x16  __attribute__((ext_vector_type(16)));
typedef short  bf16x8  __attribute__((ext_vector_type(8)));
typedef unsigned short u16;
typedef u16    u16x8   __attribute__((ext_vector_type(8)));

static __device__ __forceinline__ u16 f2bf(float f){
  union { float f; unsigned u; } v; v.f = f;
  return (u16)((v.u + 0x7FFFu + ((v.u >> 16) & 1u)) >> 16);  // RNE
}

static __device__ __forceinline__ int cvtpk(float lo, float hi_){
  int r; asm("v_cvt_pk_bf16_f32 %0, %1, %2" : "=v"(r) : "v"(lo), "v"(hi_)); return r;
}
#define PSWAP(a,b) asm("v_permlane32_swap_b32 %0, %1" : "+v"(a), "+v"(b))

static __device__ __forceinline__ bf16x8 pack4(int a, int b, int c, int d){
  union { int i[4]; bf16x8 v; } u; u.i[0]=a; u.i[1]=b; u.i[2]=c; u.i[3]=d; return u.v;
}
static __device__ __forceinline__ float hsum16(f32x16 v){
  float a0=v[0]+v[1], a1=v[2]+v[3], a2=v[4]+v[5], a3=v[6]+v[7];
  float a4=v[8]+v[9], a5=v[10]+v[11], a6=v[12]+v[13], a7=v[14]+v[15];
  float b0=a0+a1, b1=a2+a3, b2=a4+a5, b3=a6+a7;
  return (b0+b1)+(b2+b3);
}

// async global->LDS, 16B per lane; LDS dest is wave-uniform base (+lane*16 in HW)
#define GLDS16(gp, lp) __builtin_amdgcn_global_load_lds( \
    (const __attribute__((address_space(1))) void*)(gp), \
    (__attribute__((address_space(3))) void*)(lp), 16, 0, 0)

#define MFMA32(a,b,c) __builtin_amdgcn_mfma_f32_32x32x16_bf16(a,b,c,0,0,0)
#define VMCNT0() asm volatile("s_waitcnt vmcnt(0)" ::: "memory")

// ---------------------------------------------------------------- convert
struct ConvArgs {
  const float* src[7];
  u16* dst[7];
  int n8[7];
};

__global__ __launch_bounds__(256) void cvt_all(ConvArgs a){
  int z = blockIdx.z;
  const float* s = a.src[z];
  u16* d = a.dst[z];
  int n8 = a.n8[z];
  int stride = gridDim.x * blockDim.x;
  for (int i = blockIdx.x * blockDim.x + threadIdx.x; i < n8; i += stride){
    const float4* sp = (const float4*)s;
    float4 f0 = sp[2*i];
    float4 f1 = sp[2*i+1];
    u16x8 o;
    o[0]=f2bf(f0.x); o[1]=f2bf(f0.y); o[2]=f2bf(f0.z); o[3]=f2bf(f0.w);
    o[4]=f2bf(f1.x); o[5]=f2bf(f1.y); o[6]=f2bf(f1.z); o[7]=f2bf(f1.w);
    *(u16x8*)(d + 8*(size_t)i) = o;
  }
}

// ---------------------------------------------------------------- GEMM
// C[M,N] = A[M,K] * W[N,K]^T (+bias)*scale ; 128x128 tile, BK=64, 4 waves.
struct GemmArgs {
  const u16* A[3];
  const u16* W[3];
  const float* bias[3];
  void* C[3];
  float scale[3];
};

template<bool F32OUT>
__global__ __launch_bounds__(256, 3) void gemm_bt(GemmArgs g){
  const int Kd = DM;
  const int Nd = DM;
  int z = blockIdx.z;
  const u16* A = g.A[z];
  const u16* W = g.W[z];
  const float* bias = g.bias[z];
  float scale = g.scale[z];

  int col0 = blockIdx.x * 128;
  int row0 = blockIdx.y * 128;

  __shared__ u16 sA[128*64];
  __shared__ u16 sB[128*64];

  int t = threadIdx.x, lane = t & 63, wave = t >> 6;
  int wm = wave >> 1, wn = wave & 1;

  f32x4 acc[4][4];
  #pragma unroll
  for (int i=0;i<4;++i)
    #pragma unroll
    for (int j=0;j<4;++j){ acc[i][j][0]=0.f; acc[i][j][1]=0.f; acc[i][j][2]=0.f; acc[i][j][3]=0.f; }

  const char* Abase = (const char*)A + (size_t)row0 * (Kd*2);
  const char* Wbase = (const char*)W + (size_t)col0 * (Kd*2);

  for (int kt = 0; kt < Kd/64; ++kt){
    __syncthreads();
    #pragma unroll
    for (int i=0;i<4;++i){
      int li = i*256 + t;
      int r = li >> 3, c16 = li & 7;
      int cb = (c16*16) ^ ((r & 7) << 4);
      GLDS16(Abase + (size_t)r*(Kd*2) + kt*128 + cb, &sA[(size_t)(i*256 + wave*64)*8]);
      GLDS16(Wbase + (size_t)r*(Kd*2) + kt*128 + cb, &sB[(size_t)(i*256 + wave*64)*8]);
    }
    __syncthreads();

    #pragma unroll
    for (int ks=0; ks<2; ++ks){
      bf16x8 af[4], bw[4];
      #pragma unroll
      for (int mf=0; mf<4; ++mf){
        int r = wm*64 + mf*16 + (lane & 15);
        int cb = (ks*64 + ((lane>>4)<<4)) ^ ((r & 7) << 4);
        af[mf] = *(const bf16x8*)((const char*)sA + r*128 + cb);
      }
      #pragma unroll
      for (int nf=0; nf<4; ++nf){
        int r = wn*64 + nf*16 + (lane & 15);
        int cb = (ks*64 + ((lane>>4)<<4)) ^ ((r & 7) << 4);
        bw[nf] = *(const bf16x8*)((const char*)sB + r*128 + cb);
      }
      #pragma unroll
      for (int mf=0; mf<4; ++mf)
        #pragma unroll
        for (int nf=0; nf<4; ++nf)
          acc[mf][nf] = __builtin_amdgcn_mfma_f32_16x16x32_bf16(af[mf], bw[nf], acc[mf][nf], 0, 0, 0);
    }
  }

  #pragma unroll
  for (int mf=0; mf<4; ++mf){
    int rbase = row0 + wm*64 + mf*16 + ((lane>>4)<<2);
    #pragma unroll
    for (int nf=0; nf<4; ++nf){
      int col = col0 + wn*64 + nf*16 + (lane & 15);
      float bv = bias[col];
      f32x4 v = acc[mf][nf];
      #pragma unroll
      for (int j=0;j<4;++j){
        float o = (v[j] + bv) * scale;
        if (F32OUT) ((float*)g.C[z])[(size_t)(rbase+j)*Nd + col] = o;
        else        ((u16*)  g.C[z])[(size_t)(rbase+j)*Nd + col] = f2bf(o);
      }
    }
  }
}

// ---------------------------------------------------------------- V transpose
__global__ __launch_bounds__(256) void transpose_v(const u16* __restrict__ V, u16* __restrict__ Vt){
  int st = blockIdx.x;
  int h  = blockIdx.y;
  int b  = blockIdx.z;
  __shared__ u16 T[64][72];
  int t = threadIdx.x;
  const u16* src = V + ((size_t)(b*Sc + st*64))*DM + h*64;
  #pragma unroll
  for (int i=0;i<4;++i){
    int li = i*256 + t;
    int r = li >> 4, c4 = li & 15;
    ushort4 v = *(const ushort4*)(src + (size_t)r*DM + c4*4);
    T[r][c4*4+0]=v.x; T[r][c4*4+1]=v.y; T[r][c4*4+2]=v.z; T[r][c4*4+3]=v.w;
  }
  __syncthreads();
  u16* dst = Vt + ((size_t)((b*NH + h)*DKc))*Sc + st*64;
  #pragma unroll
  for (int i=0;i<4;++i){
    int li = i*256 + t;
    int d = li >> 4, s4 = li & 15;
    ushort4 v;
    v.x = T[s4*4+0][d]; v.y = T[s4*4+1][d]; v.z = T[s4*4+2][d]; v.w = T[s4*4+3][d];
    *(ushort4*)(dst + (size_t)d*Sc + s4*4) = v;
  }
}

// ---------------------------------------------------------------- flash attention v6
// R4's verified skeleton verbatim: interleaved K|V 256B rows + 4-bit XOR swizzle
// (0 bank conflicts), 3-buffer ring, 2 barriers/tile, counted vmcnt(8), per-kt
// recomputed STAGE addresses. Single delta vs R4: qpw=32 (R3-verified compute/
// epilogue), grid (64 bh, 16 qt), launch_bounds(256,4).
__global__ __launch_bounds__(256, 4) void attn32(
    const u16* __restrict__ Q, const u16* __restrict__ K, const u16* __restrict__ Vt,
    const float* __restrict__ mask, u16* __restrict__ AO){
  int bh = blockIdx.x;
  int qt = blockIdx.y;
  int b = bh >> 4, h = bh & 15;
  int t = threadIdx.x, lane = t & 63, wave = t >> 6;
  int lq = lane & 31, hi = lane >> 5;

  // row r (0..63): K-key r (bytes 0..127) ++ V-dim r (bytes 128..255);
  // physical byte = r*256 + (col ^ ((r&15)<<4)); source pre-swizzled.
  __shared__ u16 sT[3][64*128];    // 3 x 16KB
  __shared__ float sL[128];

  const float* maskB = mask + (size_t)b*Sc;
  int bad = 0;
  #pragma unroll
  for (int i=0;i<8;++i){
    float mv = maskB[i*256 + t];
    bad |= !(mv > 0.5f);
  }
  int allkeep = __syncthreads_and(!bad);

  int qbase = qt*128 + wave*32;

  // Q fragments (B-operand): col=q=lq, k-elem = 8*hi+e within d-chunk ks*16
  bf16x8 qf[4];
  {
    const u16* qp = Q + ((size_t)(b*Sc + qbase + lq))*DM + h*64 + hi*8;
    #pragma unroll
    for (int ks=0; ks<4; ++ks)
      qf[ks] = *(const bf16x8*)(qp + ks*16);
  }

  f32x16 O0, O1, lv;
  #pragma unroll
  for (int e=0; e<16; ++e){ O0[e]=0.f; O1[e]=0.f; lv[e]=0.f; }

  const char* Kbase = (const char*)K + ((size_t)(b*Sc))*2048 + h*128;    // key stride 2048B
  const char* Vbase = (const char*)Vt + ((size_t)((b*NH + h)*DKc))*4096; // d stride 4096B

  auto STAGE = [&](int bb, int kt) __attribute__((always_inline)) {
    #pragma unroll
    for (int i=0;i<4;++i){
      int row = i*16 + (t >> 4);             // 0..63
      int c16 = (t & 15) ^ (row & 15);       // inverse swizzle on source
      const char* srcK = Kbase + (size_t)(kt*64 + row)*2048 + c16*16;
      const char* srcV = Vbase + (size_t)row*4096 + kt*128 + (c16-8)*16;
      const char* src = (c16 < 8) ? srcK : srcV;
      GLDS16(src, &sT[bb][(size_t)(i*256 + wave*64)*8]);
    }
  };

  // prologue: fill 3-deep
  STAGE(0, 0);
  STAGE(1, 1);
  STAGE(2, 2);
  asm volatile("s_waitcnt vmcnt(8)" ::: "memory");   // stage 0 landed (per wave)
  __builtin_amdgcn_s_barrier();

  int cur = 0;
  for (int kt=0; kt<32; ++kt){
    const char* bufc = (const char*)(&sT[cur][0]);
    int swz = (lq & 15) << 4;

    #pragma unroll
    for (int kb=0; kb<2; ++kb){
      f32x16 s0;
      #pragma unroll
      for (int e=0; e<16; ++e) s0[e]=0.f;
      {
        const char* kr = bufc + (kb*32 + lq)*256;
        bf16x8 kf0 = *(const bf16x8*)(kr + ((0*32 + hi*16) ^ swz));
        bf16x8 kf1 = *(const bf16x8*)(kr + ((1*32 + hi*16) ^ swz));
        bf16x8 kf2 = *(const bf16x8*)(kr + ((2*32 + hi*16) ^ swz));
        bf16x8 kf3 = *(const bf16x8*)(kr + ((3*32 + hi*16) ^ swz));
        __builtin_amdgcn_s_setprio(1);
        s0 = MFMA32(kf0, qf[0], s0);
        s0 = MFMA32(kf1, qf[1], s0);
        s0 = MFMA32(kf2, qf[2], s0);
        s0 = MFMA32(kf3, qf[3], s0);
        __builtin_amdgcn_s_setprio(0);
      }
      if (!allkeep){
        // slow path (never taken for all-ones mask)
        #pragma unroll
        for (int c=0;c<4;++c)
          #pragma unroll
          for (int j=0;j<4;++j){
            int key = kt*64 + kb*32 + c*8 + j + hi*4;
            float mv = maskB[key];
            if (!(mv > 0.5f)) s0[c*4+j] += -1e9f;
          }
      }
      #pragma unroll
      for (int e=0; e<16; ++e) s0[e] = __builtin_amdgcn_exp2f(s0[e]);
      lv += s0;

      #pragma unroll
      for (int h16=0; h16<2; ++h16){
        int o = h16*8;
        int a0 = cvtpk(s0[o+0],s0[o+1]), a1 = cvtpk(s0[o+2],s0[o+3]);
        int a2 = cvtpk(s0[o+4],s0[o+5]), a3 = cvtpk(s0[o+6],s0[o+7]);
        PSWAP(a0, a2); PSWAP(a1, a3);
        bf16x8 pa = pack4(a0,a1,a2,a3);
        int kcol = 128 + kb*64 + h16*32 + hi*16;          // V half of the row
        bf16x8 vf0 = *(const bf16x8*)(bufc + (0*32 + lq)*256 + (kcol ^ swz));
        bf16x8 vf1 = *(const bf16x8*)(bufc + (32 + lq)*256 + (kcol ^ swz));
        __builtin_amdgcn_s_setprio(1);
        O0 = MFMA32(pa, vf0, O0);
        O1 = MFMA32(pa, vf1, O1);
        __builtin_amdgcn_s_setprio(0);
      }
    }

    // pipeline turn: all waves done reading buf[cur]; refill it 3 ahead; wait kt+1.
    __builtin_amdgcn_sched_barrier(0);
    __builtin_amdgcn_s_barrier();
    int nst = (kt+3 <= 31) ? (kt+3) : 31;
    STAGE(cur, nst);
    asm volatile("s_waitcnt vmcnt(8)" ::: "memory");     // stage kt+1 landed
    __builtin_amdgcn_s_barrier();
    __builtin_amdgcn_sched_barrier(0);
    cur = (cur == 2) ? 0 : cur + 1;
  }

  // epilogue
  float l0 = hsum16(lv);
  float lt = l0 + __shfl_xor(l0, 32);
  sL[wave*32 + lq] = 1.0f / lt;
  __syncthreads();

  #pragma unroll
  for (int reg=0; reg<16; ++reg){
    int qp = (reg & 3) + 8*(reg >> 2) + 4*hi;
    float inv = sL[wave*32 + qp];
    int qrow = qbase + qp;
    u16* dst = AO + ((size_t)(b*Sc + qrow))*DM + h*64 + lq;
    dst[0]  = f2bf(O0[reg] * inv);
    dst[32] = f2bf(O1[reg] * inv);
  }
}

// ---------------------------------------------------------------- launch
extern "C" void kernel_launch(void* const* d_in, const int* in_sizes, int n_in,
                              void* d_out, int out_size, void* d_ws, size_t ws_size,
                              hipStream_t stream) {
  const float* q    = (const float*)d_in[0];
  const float* k    = (const float*)d_in[1];
  const float* v    = (const float*)d_in[2];
  const float* mask = (const float*)d_in[3];
  const float* w_q  = (const float*)d_in[4];
  const float* b_q  = (const float*)d_in[5];
  const float* w_k  = (const float*)d_in[6];
  const float* b_k  = (const float*)d_in[7];
  const float* w_v  = (const float*)d_in[8];
  const float* b_v  = (const float*)d_in[9];
  const float* w_o  = (const float*)d_in[10];
  const float* b_o  = (const float*)d_in[11];

  const size_t E8 = (size_t)BSc * DM;
  const size_t EW = (size_t)DM * DM;
  u16* ws  = (u16*)d_ws;
  u16* qb  = ws;
  u16* kb  = ws + E8;
  u16* vb  = ws + 2*E8;
  u16* Qp  = ws + 3*E8;
  u16* Kp  = ws + 4*E8;
  u16* Vp  = ws + 5*E8;
  u16* Vtp = ws + 6*E8;
  u16* AOp = ws + 7*E8;
  u16* wqb = ws + 8*E8;
  u16* wkb = wqb + EW;
  u16* wvb = wqb + 2*EW;
  u16* wob = wqb + 3*EW;

  ConvArgs ca;
  ca.src[0]=q;  ca.src[1]=k;  ca.src[2]=v;  ca.src[3]=w_q; ca.src[4]=w_k; ca.src[5]=w_v; ca.src[6]=w_o;
  ca.dst[0]=qb; ca.dst[1]=kb; ca.dst[2]=vb; ca.dst[3]=wqb; ca.dst[4]=wkb; ca.dst[5]=wvb; ca.dst[6]=wob;
  ca.n8[0]=ca.n8[1]=ca.n8[2]=(int)(E8/8);
  ca.n8[3]=ca.n8[4]=ca.n8[5]=ca.n8[6]=(int)(EW/8);
  cvt_all<<<dim3(1024,1,7), 256, 0, stream>>>(ca);

  // QKV projections; Q pre-scaled by (1/sqrt(64)) * log2(e) for exp2-domain softmax
  GemmArgs g1;
  g1.A[0]=qb; g1.A[1]=kb; g1.A[2]=vb;
  g1.W[0]=wqb; g1.W[1]=wkb; g1.W[2]=wvb;
  g1.bias[0]=b_q; g1.bias[1]=b_k; g1.bias[2]=b_v;
  g1.C[0]=Qp; g1.C[1]=Kp; g1.C[2]=Vp;
  g1.scale[0]=0.125f * 1.4426950408889634f; g1.scale[1]=1.f; g1.scale[2]=1.f;
  gemm_bt<false><<<dim3(8, 64, 3), 256, 0, stream>>>(g1);

  transpose_v<<<dim3(32, 16, 4), 256, 0, stream>>>(Vp, Vtp);

  attn32<<<dim3(64, 16), 256, 0, stream>>>(Qp, Kp, Vtp, mask, AOp);

  GemmArgs g2;
  g2.A[0]=AOp; g2.A[1]=AOp; g2.A[2]=AOp;
  g2.W[0]=wob; g2.W[1]=wob; g2.W[2]=wob;
  g2.bias[0]=b_o; g2.bias[1]=b_o; g2.bias[2]=b_o;
  g2.C[0]=d_out; g2.C[1]=d_out; g2.C[2]=d_out;
  g2.scale[0]=1.f; g2.scale[1]=1.f; g2.scale[2]=1.f;
  gemm_bt<true><<<dim3(8, 64, 1), 256, 0, stream>>>(g2);
}

// Round 8
// 206.857 us; speedup vs baseline: 1.0877x; 1.0877x over previous
//
#include <hip/hip_runtime.h>
#include <stdint.h>

#define DM   1024
#define NH   16
#define DKc  64
#define Bc   4
#define Sc   2048
#define BSc  (Bc*Sc)

typedef float  f32x4   __attribute__((ext_vector_type(4)));
typedef float  f32x16  __attribute__((ext_vector_type(16)));
typedef short  bf16x8  __attribute__((ext_vector_type(8)));
typedef unsigned short u16;
typedef u16    u16x8   __attribute__((ext_vector_type(8)));

static __device__ __forceinline__ u16 f2bf(float f){
  union { float f; unsigned u; } v; v.f = f;
  return (u16)((v.u + 0x7FFFu + ((v.u >> 16) & 1u)) >> 16);  // RNE
}

static __device__ __forceinline__ int cvtpk(float lo, float hi_){
  int r; asm("v_cvt_pk_bf16_f32 %0, %1, %2" : "=v"(r) : "v"(lo), "v"(hi_)); return r;
}
#define PSWAP(a,b) asm("v_permlane32_swap_b32 %0, %1" : "+v"(a), "+v"(b))

static __device__ __forceinline__ bf16x8 pack4(int a, int b, int c, int d){
  union { int i[4]; bf16x8 v; } u; u.i[0]=a; u.i[1]=b; u.i[2]=c; u.i[3]=d; return u.v;
}

// async global->LDS, 16B per lane; LDS dest is wave-uniform base (+lane*16 in HW)
#define GLDS16(gp, lp) __builtin_amdgcn_global_load_lds( \
    (const __attribute__((address_space(1))) void*)(gp), \
    (__attribute__((address_space(3))) void*)(lp), 16, 0, 0)

#define MFMA32(a,b,c) __builtin_amdgcn_mfma_f32_32x32x16_bf16(a,b,c,0,0,0)
#define VMCNT0() asm volatile("s_waitcnt vmcnt(0)" ::: "memory")

// ---------------------------------------------------------------- convert
struct ConvArgs {
  const float* src[7];
  u16* dst[7];
  int n8[7];
};

__global__ __launch_bounds__(256) void cvt_all(ConvArgs a){
  int z = blockIdx.z;
  const float* s = a.src[z];
  u16* d = a.dst[z];
  int n8 = a.n8[z];
  int stride = gridDim.x * blockDim.x;
  for (int i = blockIdx.x * blockDim.x + threadIdx.x; i < n8; i += stride){
    const float4* sp = (const float4*)s;
    float4 f0 = sp[2*i];
    float4 f1 = sp[2*i+1];
    u16x8 o;
    o[0]=f2bf(f0.x); o[1]=f2bf(f0.y); o[2]=f2bf(f0.z); o[3]=f2bf(f0.w);
    o[4]=f2bf(f1.x); o[5]=f2bf(f1.y); o[6]=f2bf(f1.z); o[7]=f2bf(f1.w);
    *(u16x8*)(d + 8*(size_t)i) = o;
  }
}

// ---------------------------------------------------------------- GEMM
// C[M,N] = A[M,K] * W[N,K]^T (+bias)*scale ; 128x128 tile, BK=64, 4 waves.
struct GemmArgs {
  const u16* A[3];
  const u16* W[3];
  const float* bias[3];
  void* C[3];
  float scale[3];
};

template<bool F32OUT>
__global__ __launch_bounds__(256, 3) void gemm_bt(GemmArgs g){
  const int Kd = DM;
  const int Nd = DM;
  int z = blockIdx.z;
  const u16* A = g.A[z];
  const u16* W = g.W[z];
  const float* bias = g.bias[z];
  float scale = g.scale[z];

  int col0 = blockIdx.x * 128;
  int row0 = blockIdx.y * 128;

  __shared__ u16 sA[128*64];
  __shared__ u16 sB[128*64];

  int t = threadIdx.x, lane = t & 63, wave = t >> 6;
  int wm = wave >> 1, wn = wave & 1;

  f32x4 acc[4][4];
  #pragma unroll
  for (int i=0;i<4;++i)
    #pragma unroll
    for (int j=0;j<4;++j){ acc[i][j][0]=0.f; acc[i][j][1]=0.f; acc[i][j][2]=0.f; acc[i][j][3]=0.f; }

  const char* Abase = (const char*)A + (size_t)row0 * (Kd*2);
  const char* Wbase = (const char*)W + (size_t)col0 * (Kd*2);

  for (int kt = 0; kt < Kd/64; ++kt){
    __syncthreads();
    #pragma unroll
    for (int i=0;i<4;++i){
      int li = i*256 + t;
      int r = li >> 3, c16 = li & 7;
      int cb = (c16*16) ^ ((r & 7) << 4);
      GLDS16(Abase + (size_t)r*(Kd*2) + kt*128 + cb, &sA[(size_t)(i*256 + wave*64)*8]);
      GLDS16(Wbase + (size_t)r*(Kd*2) + kt*128 + cb, &sB[(size_t)(i*256 + wave*64)*8]);
    }
    __syncthreads();

    #pragma unroll
    for (int ks=0; ks<2; ++ks){
      bf16x8 af[4], bw[4];
      #pragma unroll
      for (int mf=0; mf<4; ++mf){
        int r = wm*64 + mf*16 + (lane & 15);
        int cb = (ks*64 + ((lane>>4)<<4)) ^ ((r & 7) << 4);
        af[mf] = *(const bf16x8*)((const char*)sA + r*128 + cb);
      }
      #pragma unroll
      for (int nf=0; nf<4; ++nf){
        int r = wn*64 + nf*16 + (lane & 15);
        int cb = (ks*64 + ((lane>>4)<<4)) ^ ((r & 7) << 4);
        bw[nf] = *(const bf16x8*)((const char*)sB + r*128 + cb);
      }
      #pragma unroll
      for (int mf=0; mf<4; ++mf)
        #pragma unroll
        for (int nf=0; nf<4; ++nf)
          acc[mf][nf] = __builtin_amdgcn_mfma_f32_16x16x32_bf16(af[mf], bw[nf], acc[mf][nf], 0, 0, 0);
    }
  }

  #pragma unroll
  for (int mf=0; mf<4; ++mf){
    int rbase = row0 + wm*64 + mf*16 + ((lane>>4)<<2);
    #pragma unroll
    for (int nf=0; nf<4; ++nf){
      int col = col0 + wn*64 + nf*16 + (lane & 15);
      float bv = bias[col];
      f32x4 v = acc[mf][nf];
      #pragma unroll
      for (int j=0;j<4;++j){
        float o = (v[j] + bv) * scale;
        if (F32OUT) ((float*)g.C[z])[(size_t)(rbase+j)*Nd + col] = o;
        else        ((u16*)  g.C[z])[(size_t)(rbase+j)*Nd + col] = f2bf(o);
      }
    }
  }
}

// ---------------------------------------------------------------- V transpose
__global__ __launch_bounds__(256) void transpose_v(const u16* __restrict__ V, u16* __restrict__ Vt){
  int st = blockIdx.x;
  int h  = blockIdx.y;
  int b  = blockIdx.z;
  __shared__ u16 T[64][72];
  int t = threadIdx.x;
  const u16* src = V + ((size_t)(b*Sc + st*64))*DM + h*64;
  #pragma unroll
  for (int i=0;i<4;++i){
    int li = i*256 + t;
    int r = li >> 4, c4 = li & 15;
    ushort4 v = *(const ushort4*)(src + (size_t)r*DM + c4*4);
    T[r][c4*4+0]=v.x; T[r][c4*4+1]=v.y; T[r][c4*4+2]=v.z; T[r][c4*4+3]=v.w;
  }
  __syncthreads();
  u16* dst = Vt + ((size_t)((b*NH + h)*DKc))*Sc + st*64;
  #pragma unroll
  for (int i=0;i<4;++i){
    int li = i*256 + t;
    int d = li >> 4, s4 = li & 15;
    ushort4 v;
    v.x = T[s4*4+0][d]; v.y = T[s4*4+1][d]; v.z = T[s4*4+2][d]; v.w = T[s4*4+3][d];
    *(ushort4*)(dst + (size_t)d*Sc + s4*4) = v;
  }
}

// ---------------------------------------------------------------- flash attention v7
// Swapped 32x32, qpw=64. R2-verified sync skeleton (2-buf, stage-at-top, one
// vmcnt(0)+barrier per kt), R4-verified interleaved K|V layout (0 conflicts),
// R4-verbatim per-kt STAGE address math. NEW: cross-kb ILP ordering
// (QK0,QK1 issued before softmax0 so MFMA overlaps VALU/trans) and l via
// MFMA(pa, ones) into Lacc (kills lv adds + epilogue reduction/LDS).
__global__ __launch_bounds__(256, 2) void attn32(
    const u16* __restrict__ Q, const u16* __restrict__ K, const u16* __restrict__ Vt,
    const float* __restrict__ mask, u16* __restrict__ AO){
  int bh = blockIdx.x;
  int qt = blockIdx.y;
  int b = bh >> 4, h = bh & 15;
  int t = threadIdx.x, lane = t & 63, wave = t >> 6;
  int lq = lane & 31, hi = lane >> 5;

  // row r (0..63): K-key r (bytes 0..127) ++ V-dim r (bytes 128..255);
  // physical byte = r*256 + (col ^ ((r&15)<<4)); source pre-swizzled.
  __shared__ u16 sT[2][64*128];    // 2 x 16KB

  const float* maskB = mask + (size_t)b*Sc;
  int bad = 0;
  #pragma unroll
  for (int i=0;i<8;++i){
    float mv = maskB[i*256 + t];
    bad |= !(mv > 0.5f);
  }
  int allkeep = __syncthreads_and(!bad);

  int qbase = qt*256 + wave*64;

  // Q fragments (B-operand): col=q=lq, k-elem = 8*hi+e within d-chunk ks*16
  bf16x8 qf0[4], qf1[4];
  {
    const u16* qp0 = Q + ((size_t)(b*Sc + qbase + lq))*DM + h*64 + hi*8;
    const u16* qp1 = Q + ((size_t)(b*Sc + qbase + 32 + lq))*DM + h*64 + hi*8;
    #pragma unroll
    for (int ks=0; ks<4; ++ks){
      qf0[ks] = *(const bf16x8*)(qp0 + ks*16);
      qf1[ks] = *(const bf16x8*)(qp1 + ks*16);
    }
  }

  // all-ones bf16 B-operand for l accumulation (layout-independent)
  bf16x8 ones;
  #pragma unroll
  for (int e=0; e<8; ++e) ones[e] = (short)0x3F80;

  f32x16 O00, O01, O10, O11, L0, L1;
  #pragma unroll
  for (int e=0; e<16; ++e){ O00[e]=0.f; O01[e]=0.f; O10[e]=0.f; O11[e]=0.f; L0[e]=0.f; L1[e]=0.f; }

  const char* Kbase = (const char*)K + ((size_t)(b*Sc))*2048 + h*128;    // key stride 2048B
  const char* Vbase = (const char*)Vt + ((size_t)((b*NH + h)*DKc))*4096; // d stride 4096B

  auto STAGE = [&](int bb, int kt) __attribute__((always_inline)) {
    #pragma unroll
    for (int i=0;i<4;++i){
      int row = i*16 + (t >> 4);             // 0..63
      int c16 = (t & 15) ^ (row & 15);       // inverse swizzle on source
      const char* srcK = Kbase + (size_t)(kt*64 + row)*2048 + c16*16;
      const char* srcV = Vbase + (size_t)row*4096 + kt*128 + (c16-8)*16;
      const char* src = (c16 < 8) ? srcK : srcV;
      GLDS16(src, &sT[bb][(size_t)(i*256 + wave*64)*8]);
    }
  };

  // prologue
  STAGE(0, 0);
  VMCNT0();
  __builtin_amdgcn_s_barrier();

  int cur = 0;
  for (int kt=0; kt<32; ++kt){
    if (kt < 31) STAGE(cur^1, kt+1);         // loads for kt+1 fly during compute

    const char* bufc = (const char*)(&sT[cur][0]);
    int swz = (lq & 15) << 4;

    f32x16 s00, s01, s10, s11;               // [kb][qb]
    #pragma unroll
    for (int e=0; e<16; ++e){ s00[e]=0.f; s01[e]=0.f; s10[e]=0.f; s11[e]=0.f; }

    // ---- QK for kb=0
    {
      const char* kr = bufc + (0*32 + lq)*256;
      bf16x8 k0 = *(const bf16x8*)(kr + ((0*32 + hi*16) ^ swz));
      bf16x8 k1 = *(const bf16x8*)(kr + ((1*32 + hi*16) ^ swz));
      bf16x8 k2 = *(const bf16x8*)(kr + ((2*32 + hi*16) ^ swz));
      bf16x8 k3 = *(const bf16x8*)(kr + ((3*32 + hi*16) ^ swz));
      __builtin_amdgcn_s_setprio(1);
      s00 = MFMA32(k0, qf0[0], s00); s01 = MFMA32(k0, qf1[0], s01);
      s00 = MFMA32(k1, qf0[1], s00); s01 = MFMA32(k1, qf1[1], s01);
      s00 = MFMA32(k2, qf0[2], s00); s01 = MFMA32(k2, qf1[2], s01);
      s00 = MFMA32(k3, qf0[3], s00); s01 = MFMA32(k3, qf1[3], s01);
      __builtin_amdgcn_s_setprio(0);
    }
    // ---- QK for kb=1 (issued before softmax0 so it overlaps the VALU below)
    {
      const char* kr = bufc + (1*32 + lq)*256;
      bf16x8 k0 = *(const bf16x8*)(kr + ((0*32 + hi*16) ^ swz));
      bf16x8 k1 = *(const bf16x8*)(kr + ((1*32 + hi*16) ^ swz));
      bf16x8 k2 = *(const bf16x8*)(kr + ((2*32 + hi*16) ^ swz));
      bf16x8 k3 = *(const bf16x8*)(kr + ((3*32 + hi*16) ^ swz));
      __builtin_amdgcn_s_setprio(1);
      s10 = MFMA32(k0, qf0[0], s10); s11 = MFMA32(k0, qf1[0], s11);
      s10 = MFMA32(k1, qf0[1], s10); s11 = MFMA32(k1, qf1[1], s11);
      s10 = MFMA32(k2, qf0[2], s10); s11 = MFMA32(k2, qf1[2], s11);
      s10 = MFMA32(k3, qf0[3], s10); s11 = MFMA32(k3, qf1[3], s11);
      __builtin_amdgcn_s_setprio(0);
    }

    if (!allkeep){
      // slow path (never taken for all-ones mask)
      #pragma unroll
      for (int c=0;c<4;++c)
        #pragma unroll
        for (int j=0;j<4;++j){
          int key0 = kt*64 + 0*32 + c*8 + j + hi*4;
          int key1 = kt*64 + 1*32 + c*8 + j + hi*4;
          float mv0 = maskB[key0];
          float mv1 = maskB[key1];
          if (!(mv0 > 0.5f)){ s00[c*4+j] += -1e9f; s01[c*4+j] += -1e9f; }
          if (!(mv1 > 0.5f)){ s10[c*4+j] += -1e9f; s11[c*4+j] += -1e9f; }
        }
    }

    // ---- softmax kb=0 (QK1 MFMAs still in flight -> overlap) + PV kb=0
    #pragma unroll
    for (int e=0; e<16; ++e){ s00[e] = __builtin_amdgcn_exp2f(s00[e]); s01[e] = __builtin_amdgcn_exp2f(s01[e]); }
    #pragma unroll
    for (int h16=0; h16<2; ++h16){
      int o = h16*8;
      int a00 = cvtpk(s00[o+0],s00[o+1]), a01 = cvtpk(s00[o+2],s00[o+3]);
      int a02 = cvtpk(s00[o+4],s00[o+5]), a03 = cvtpk(s00[o+6],s00[o+7]);
      PSWAP(a00, a02); PSWAP(a01, a03);
      bf16x8 pa0 = pack4(a00,a01,a02,a03);
      int a10 = cvtpk(s01[o+0],s01[o+1]), a11 = cvtpk(s01[o+2],s01[o+3]);
      int a12 = cvtpk(s01[o+4],s01[o+5]), a13 = cvtpk(s01[o+6],s01[o+7]);
      PSWAP(a10, a12); PSWAP(a11, a13);
      bf16x8 pa1 = pack4(a10,a11,a12,a13);
      int kcol = 128 + 0*64 + h16*32 + hi*16;            // V half, kb=0
      bf16x8 vf0 = *(const bf16x8*)(bufc + (0*32 + lq)*256 + (kcol ^ swz));
      bf16x8 vf1 = *(const bf16x8*)(bufc + (32 + lq)*256 + (kcol ^ swz));
      __builtin_amdgcn_s_setprio(1);
      O00 = MFMA32(pa0, vf0, O00);
      O01 = MFMA32(pa0, vf1, O01);
      O10 = MFMA32(pa1, vf0, O10);
      O11 = MFMA32(pa1, vf1, O11);
      L0  = MFMA32(pa0, ones, L0);
      L1  = MFMA32(pa1, ones, L1);
      __builtin_amdgcn_s_setprio(0);
    }

    // ---- softmax kb=1 (PV0 MFMAs in flight -> overlap) + PV kb=1
    #pragma unroll
    for (int e=0; e<16; ++e){ s10[e] = __builtin_amdgcn_exp2f(s10[e]); s11[e] = __builtin_amdgcn_exp2f(s11[e]); }
    #pragma unroll
    for (int h16=0; h16<2; ++h16){
      int o = h16*8;
      int a00 = cvtpk(s10[o+0],s10[o+1]), a01 = cvtpk(s10[o+2],s10[o+3]);
      int a02 = cvtpk(s10[o+4],s10[o+5]), a03 = cvtpk(s10[o+6],s10[o+7]);
      PSWAP(a00, a02); PSWAP(a01, a03);
      bf16x8 pa0 = pack4(a00,a01,a02,a03);
      int a10 = cvtpk(s11[o+0],s11[o+1]), a11 = cvtpk(s11[o+2],s11[o+3]);
      int a12 = cvtpk(s11[o+4],s11[o+5]), a13 = cvtpk(s11[o+6],s11[o+7]);
      PSWAP(a10, a12); PSWAP(a11, a13);
      bf16x8 pa1 = pack4(a10,a11,a12,a13);
      int kcol = 128 + 1*64 + h16*32 + hi*16;            // V half, kb=1
      bf16x8 vf0 = *(const bf16x8*)(bufc + (0*32 + lq)*256 + (kcol ^ swz));
      bf16x8 vf1 = *(const bf16x8*)(bufc + (32 + lq)*256 + (kcol ^ swz));
      __builtin_amdgcn_s_setprio(1);
      O00 = MFMA32(pa0, vf0, O00);
      O01 = MFMA32(pa0, vf1, O01);
      O10 = MFMA32(pa1, vf0, O10);
      O11 = MFMA32(pa1, vf1, O11);
      L0  = MFMA32(pa0, ones, L0);
      L1  = MFMA32(pa1, ones, L1);
      __builtin_amdgcn_s_setprio(0);
    }

    VMCNT0();                                // stage(kt+1) had the whole compute to land
    __builtin_amdgcn_s_barrier();
    cur ^= 1;
  }

  // epilogue: 1/l already lane-aligned with O (same reg->q-row mapping)
  #pragma unroll
  for (int reg=0; reg<16; ++reg){
    int qp = (reg & 3) + 8*(reg >> 2) + 4*hi;
    float inv0 = 1.0f / L0[reg];
    float inv1 = 1.0f / L1[reg];
    u16* dst0 = AO + ((size_t)(b*Sc + qbase + qp))*DM + h*64 + lq;
    u16* dst1 = AO + ((size_t)(b*Sc + qbase + 32 + qp))*DM + h*64 + lq;
    dst0[0]  = f2bf(O00[reg] * inv0);
    dst0[32] = f2bf(O01[reg] * inv0);
    dst1[0]  = f2bf(O10[reg] * inv1);
    dst1[32] = f2bf(O11[reg] * inv1);
  }
}

// ---------------------------------------------------------------- launch
extern "C" void kernel_launch(void* const* d_in, const int* in_sizes, int n_in,
                              void* d_out, int out_size, void* d_ws, size_t ws_size,
                              hipStream_t stream) {
  const float* q    = (const float*)d_in[0];
  const float* k    = (const float*)d_in[1];
  const float* v    = (const float*)d_in[2];
  const float* mask = (const float*)d_in[3];
  const float* w_q  = (const float*)d_in[4];
  const float* b_q  = (const float*)d_in[5];
  const float* w_k  = (const float*)d_in[6];
  const float* b_k  = (const float*)d_in[7];
  const float* w_v  = (const float*)d_in[8];
  const float* b_v  = (const float*)d_in[9];
  const float* w_o  = (const float*)d_in[10];
  const float* b_o  = (const float*)d_in[11];

  const size_t E8 = (size_t)BSc * DM;
  const size_t EW = (size_t)DM * DM;
  u16* ws  = (u16*)d_ws;
  u16* qb  = ws;
  u16* kb  = ws + E8;
  u16* vb  = ws + 2*E8;
  u16* Qp  = ws + 3*E8;
  u16* Kp  = ws + 4*E8;
  u16* Vp  = ws + 5*E8;
  u16* Vtp = ws + 6*E8;
  u16* AOp = ws + 7*E8;
  u16* wqb = ws + 8*E8;
  u16* wkb = wqb + EW;
  u16* wvb = wqb + 2*EW;
  u16* wob = wqb + 3*EW;

  ConvArgs ca;
  ca.src[0]=q;  ca.src[1]=k;  ca.src[2]=v;  ca.src[3]=w_q; ca.src[4]=w_k; ca.src[5]=w_v; ca.src[6]=w_o;
  ca.dst[0]=qb; ca.dst[1]=kb; ca.dst[2]=vb; ca.dst[3]=wqb; ca.dst[4]=wkb; ca.dst[5]=wvb; ca.dst[6]=wob;
  ca.n8[0]=ca.n8[1]=ca.n8[2]=(int)(E8/8);
  ca.n8[3]=ca.n8[4]=ca.n8[5]=ca.n8[6]=(int)(EW/8);
  cvt_all<<<dim3(1024,1,7), 256, 0, stream>>>(ca);

  // QKV projections; Q pre-scaled by (1/sqrt(64)) * log2(e) for exp2-domain softmax
  GemmArgs g1;
  g1.A[0]=qb; g1.A[1]=kb; g1.A[2]=vb;
  g1.W[0]=wqb; g1.W[1]=wkb; g1.W[2]=wvb;
  g1.bias[0]=b_q; g1.bias[1]=b_k; g1.bias[2]=b_v;
  g1.C[0]=Qp; g1.C[1]=Kp; g1.C[2]=Vp;
  g1.scale[0]=0.125f * 1.4426950408889634f; g1.scale[1]=1.f; g1.scale[2]=1.f;
  gemm_bt<false><<<dim3(8, 64, 3), 256, 0, stream>>>(g1);

  transpose_v<<<dim3(32, 16, 4), 256, 0, stream>>>(Vp, Vtp);

  attn32<<<dim3(64, 8), 256, 0, stream>>>(Qp, Kp, Vtp, mask, AOp);

  GemmArgs g2;
  g2.A[0]=AOp; g2.A[1]=AOp; g2.A[2]=AOp;
  g2.W[0]=wob; g2.W[1]=wob; g2.W[2]=wob;
  g2.bias[0]=b_o; g2.bias[1]=b_o; g2.bias[2]=b_o;
  g2.C[0]=d_out; g2.C[1]=d_out; g2.C[2]=d_out;
  g2.scale[0]=1.f; g2.scale[1]=1.f; g2.scale[2]=1.f;
  gemm_bt<true><<<dim3(8, 64, 1), 256, 0, stream>>>(g2);
}